// Round 16
// baseline (2308.564 us; speedup 1.0000x reference)
//
#include <hip/hip_runtime.h>
#include <cstdint>

#define BATCH 8
#define SEQ   2048
#define DM    768
#define DI    1536
#define DS    16
#define NL    8
#define NVOCAB 512
#define BT    (BATCH*SEQ)      // 16384
#define NCHUNK 32
#define TC    (SEQ/NCHUNK)     // 64

typedef __attribute__((ext_vector_type(8))) short bf16x8;
typedef __attribute__((ext_vector_type(4))) float f32x4;

__device__ __forceinline__ unsigned short f2bf(float f){
  unsigned int u = __float_as_uint(f);
  u += 0x7fffu + ((u >> 16) & 1u);
  return (unsigned short)(u >> 16);
}
__device__ __forceinline__ float bf2f(unsigned short s){
  return __uint_as_float(((unsigned int)s) << 16);
}
__device__ __forceinline__ float sigm(float x){ return 1.0f/(1.0f + __expf(-x)); }
__device__ __forceinline__ float siluf(float x){ return x * sigm(x); }
__device__ __forceinline__ float fast_softplus(float x){
  return (x > 15.0f) ? x : __logf(1.0f + __expf(x));
}
__device__ __forceinline__ void async16(void* l, const void* g){
  __builtin_amdgcn_global_load_lds(
      (const __attribute__((address_space(1))) unsigned int*)g,
      (__attribute__((address_space(3))) unsigned int*)l, 16, 0, 0);
}
__device__ __forceinline__ float dot4(f32x4 a, f32x4 b){
  return fmaf(a[0],b[0], fmaf(a[1],b[1], fmaf(a[2],b[2], a[3]*b[3])));
}

// ---------------- weight conversion ----------------
__global__ void cvt_bf16_kernel(const float4* __restrict__ in, ushort4* __restrict__ out, int n4){
  int i = blockIdx.x*256 + threadIdx.x;
  int stride = gridDim.x*256;
  for(; i<n4; i+=stride){
    float4 v = in[i];
    ushort4 o; o.x=f2bf(v.x); o.y=f2bf(v.y); o.z=f2bf(v.z); o.w=f2bf(v.w);
    out[i]=o;
  }
}

// wcomb[l][d][k]: k<16 -> dt_w[l][d][k], else bproj_w[l][d][k-16]  (bf16)
__global__ void wcomb_kernel(const float* __restrict__ dt_w, const float* __restrict__ bproj_w,
                             unsigned short* __restrict__ out){
  int idx = blockIdx.x*256 + threadIdx.x;   // NL*DI*32 = 393216
  int k = idx & 31, ld = idx >> 5;
  float v = (k < 16) ? dt_w[(long)ld*16 + k] : bproj_w[(long)ld*16 + (k-16)];
  out[idx] = f2bf(v);
}

// ---------------- conditioning (float4, 1 wave per dm, grid (DM/4, BATCH)) ----------------
__global__ __launch_bounds__(256) void cond_kernel(const int* __restrict__ emotion,
    const int* __restrict__ style, const int* __restrict__ keysig, const int* __restrict__ modei,
    const float* __restrict__ bpm, const float* __restrict__ emo_emb, const float* __restrict__ sty_emb,
    const float* __restrict__ key_emb, const float* __restrict__ mode_emb,
    const float* __restrict__ bpm_w, const float* __restrict__ bpm_b,
    const float* __restrict__ cond_w, const float* __restrict__ cond_b,
    float* __restrict__ cond_out){
  int b = blockIdx.y;
  int tid = threadIdx.x;
  __shared__ float vec[5*DM];        // 3840 f32 = 960 float4
  int e = emotion[b], st = style[b], ks = keysig[b], md = modei[b];
  float bp = bpm[b];
  for(int j=tid; j<960; j+=256){
    int seg = j/192, o4 = j - seg*192;
    float4 v;
    if(seg==0)      v = reinterpret_cast<const float4*>(emo_emb + (long)e*DM)[o4];
    else if(seg==1) v = reinterpret_cast<const float4*>(sty_emb + (long)st*DM)[o4];
    else if(seg==2) v = reinterpret_cast<const float4*>(key_emb + (long)ks*DM)[o4];
    else if(seg==3) v = reinterpret_cast<const float4*>(mode_emb + (long)md*DM)[o4];
    else {
      float4 w = reinterpret_cast<const float4*>(bpm_w)[o4];
      float4 bb = reinterpret_cast<const float4*>(bpm_b)[o4];
      v = make_float4(fmaf(bp,w.x,bb.x), fmaf(bp,w.y,bb.y), fmaf(bp,w.z,bb.z), fmaf(bp,w.w,bb.w));
    }
    reinterpret_cast<float4*>(vec)[j] = v;
  }
  __syncthreads();
  int wid = tid>>6, lane = tid&63;
  int dm = blockIdx.x*4 + wid;
  const float4* w4 = reinterpret_cast<const float4*>(cond_w + (long)dm*(5*DM));
  const float4* v4 = reinterpret_cast<const float4*>(vec);
  float acc = 0.f;
  #pragma unroll 5
  for(int j=lane; j<960; j+=64){
    float4 w = w4[j], v = v4[j];
    acc = fmaf(w.x,v.x, fmaf(w.y,v.y, fmaf(w.z,v.z, fmaf(w.w,v.w, acc))));
  }
  #pragma unroll
  for(int off=32; off>0; off>>=1) acc += __shfl_xor(acc, off);
  if(lane==0) cond_out[b*DM + dm] = acc + cond_b[dm];
}

// x = tok_emb[tokens] + cond + pos_emb
__global__ void embed_kernel(const int* __restrict__ tokens, const float* __restrict__ tok_emb,
    const float* __restrict__ cond, const float* __restrict__ pos_emb, float* __restrict__ x){
  int bt = blockIdx.x;
  int b = bt >> 11, t = bt & 2047;
  int tok = tokens[bt];
  const float4* te = reinterpret_cast<const float4*>(tok_emb + (long)tok*DM);
  const float4* ce = reinterpret_cast<const float4*>(cond + (long)b*DM);
  const float4* pe = reinterpret_cast<const float4*>(pos_emb + (long)t*DM);
  float4* xo = reinterpret_cast<float4*>(x + (long)bt*DM);
  int i = threadIdx.x;  // 0..191
  float4 a = te[i], c = ce[i], p = pe[i];
  xo[i] = make_float4(a.x+c.x+p.x, a.y+c.y+p.y, a.z+c.z+p.z, a.w+c.w+p.w);
}

// ---------------- layernorm -> bf16 ----------------
__global__ __launch_bounds__(256) void ln_bf16_kernel(const float* __restrict__ x,
                     const float* __restrict__ g, const float* __restrict__ bta,
                     unsigned short* __restrict__ out){
  int row  = blockIdx.x*4 + (threadIdx.x >> 6);
  int lane = threadIdx.x & 63;
  const float* xr = x + (long)row*DM;
  float4 v[3];
  float sum=0.f, sq=0.f;
  #pragma unroll
  for(int i=0;i<3;i++){
    v[i] = *reinterpret_cast<const float4*>(xr + i*256 + lane*4);
    sum += v[i].x + v[i].y + v[i].z + v[i].w;
    sq  += v[i].x*v[i].x + v[i].y*v[i].y + v[i].z*v[i].z + v[i].w*v[i].w;
  }
  #pragma unroll
  for(int off=32; off>0; off>>=1){
    sum += __shfl_xor(sum, off);
    sq  += __shfl_xor(sq , off);
  }
  float mu  = sum * (1.0f/DM);
  float var = sq  * (1.0f/DM) - mu*mu;
  float rs  = rsqrtf(var + 1e-5f);
  unsigned short* orow = out + (long)row*DM;
  #pragma unroll
  for(int i=0;i<3;i++){
    int d = i*256 + lane*4;
    float4 gg = *reinterpret_cast<const float4*>(g + d);
    float4 bb = *reinterpret_cast<const float4*>(bta + d);
    ushort4 o;
    o.x = f2bf((v[i].x - mu)*rs*gg.x + bb.x);
    o.y = f2bf((v[i].y - mu)*rs*gg.y + bb.y);
    o.z = f2bf((v[i].z - mu)*rs*gg.z + bb.z);
    o.w = f2bf((v[i].w - mu)*rs*gg.w + bb.w);
    *reinterpret_cast<ushort4*>(orow + d) = o;
  }
}

// ---------------- LDS-staged GEMM, BK=64 + T2 XOR swizzle (round-11 exact): C = A * B^T
template<int MODE>
__global__ __launch_bounds__(256) void gemm_lds(const unsigned short* __restrict__ A,
                                               const unsigned short* __restrict__ B,
                                               void* __restrict__ Cv,
                                               const float* __restrict__ bias,
                                               int K, int ldc){
  __shared__ short As[128*64];   // 16 KiB
  __shared__ short Bs[128*64];   // 16 KiB
  const short* Ap = (const short*)A;
  const short* Bp = (const short*)B;
  int tid  = threadIdx.x;
  int lane = tid & 63;
  int wid  = tid >> 6;

  int nbx = gridDim.x;
  int id  = blockIdx.y*nbx + blockIdx.x;
  int q   = (nbx*gridDim.y) >> 3;
  int swz = (id & 7)*q + (id >> 3);
  int bx  = swz % nbx, by = swz / nbx;
  int row0 = by*128;
  int col0 = bx*128;

  int srow[4], goff[4];
  #pragma unroll
  for(int j=0;j<4;j++){
    int c = j*256 + tid;
    int row = c>>3, s = c&7;
    srow[j] = row;
    goff[j] = (s ^ (row&7))*8;
  }

  int wr = (wid>>1)*64;
  int wc = (wid&1)*64;
  int fr = lane & 15;
  int kq = lane >> 4;
  int fx = fr & 7;

  f32x4 acc[4][4];
  #pragma unroll
  for(int m=0;m<4;m++)
    #pragma unroll
    for(int n=0;n<4;n++)
      acc[m][n] = (f32x4){0.f,0.f,0.f,0.f};

  for(int kt=0; kt<K; kt+=64){
    #pragma unroll
    for(int j=0;j<4;j++){
      int c = j*256 + tid;
      async16((char*)As + c*16, Ap + (long)(row0+srow[j])*K + kt + goff[j]);
      async16((char*)Bs + c*16, Bp + (long)(col0+srow[j])*K + kt + goff[j]);
    }
    __syncthreads();
    #pragma unroll
    for(int ks=0; ks<2; ks++){
      int sA = ((ks*4 + kq) ^ fx) * 8;
      bf16x8 av[4], bv[4];
      #pragma unroll
      for(int m=0;m<4;m++)
        av[m] = *reinterpret_cast<const bf16x8*>(As + (wr + m*16 + fr)*64 + sA);
      #pragma unroll
      for(int n=0;n<4;n++)
        bv[n] = *reinterpret_cast<const bf16x8*>(Bs + (wc + n*16 + fr)*64 + sA);
      #pragma unroll
      for(int m=0;m<4;m++)
        #pragma unroll
        for(int n=0;n<4;n++)
          acc[m][n] = __builtin_amdgcn_mfma_f32_16x16x32_bf16(av[m], bv[n], acc[m][n], 0, 0, 0);
    }
    __syncthreads();
  }

  int rr = (lane >> 4) << 2;
  int cc = lane & 15;
  #pragma unroll
  for(int m=0;m<4;m++){
    #pragma unroll
    for(int n=0;n<4;n++){
      int col = col0 + wc + n*16 + cc;
      #pragma unroll
      for(int i=0;i<4;i++){
        long idx = (long)(row0 + wr + m*16 + rr + i)*ldc + col;
        float v = acc[m][n][i];
        if(MODE==3)      ((unsigned short*)Cv)[idx] = f2bf(v);
        else if(MODE==1) ((float*)Cv)[idx] += v;
        else if(MODE==2) ((float*)Cv)[idx] = v + bias[col];
        else             ((float*)Cv)[idx] = v;
      }
    }
  }
}

// ---------------- 256x256 GEMM, 8 waves, BK=32, 4-buffer depth-2 pipeline, counted vmcnt ----------------
// Per iter: STAGE(t+2) -> vmcnt(8) [tile t done; t+1,t+2 in flight] -> barrier -> 32 MFMA/wave.
// 4 buffers give WAR distance 2 => single barrier per K-tile is safe.
// Swizzle (rule #21, BK=32): source col (s^(row&3))*8 ; read slot (kq^(fr&3))*8 ; 2-way banks.
template<int MODE>
__global__ __launch_bounds__(512) void gemm256(const unsigned short* __restrict__ A,
                                               const unsigned short* __restrict__ B,
                                               void* __restrict__ Cv,
                                               int K, int ldc){
  __shared__ short smem[4][2][256*32];   // [buf][A|B] : 128 KiB
  const short* Ap = (const short*)A;
  const short* Bp = (const short*)B;
  int tid  = threadIdx.x;        // 0..511
  int lane = tid & 63;
  int wid  = tid >> 6;           // 0..7

  int nbx = gridDim.x;
  int id  = blockIdx.y*nbx + blockIdx.x;
  int q   = (nbx*gridDim.y) >> 3;
  int swz = (id & 7)*q + (id >> 3);
  int bx  = swz % nbx, by = swz / nbx;
  int row0 = by*256;
  int col0 = bx*256;

  // staging: 1024 16B-chunks per matrix; chunk c: row=c>>2, s=c&3, src col=(s^(row&3))*8
  int srow[2], goff[2];
  #pragma unroll
  for(int j=0;j<2;j++){
    int c = j*512 + tid;
    int row = c>>2, s = c&3;
    srow[j] = row;
    goff[j] = (s ^ (row&3))*8;
  }

  int wr = (wid>>2)*128;         // wave M-offset (0 or 128)
  int wc = (wid&3)*64;           // wave N-offset (0,64,128,192)
  int fr = lane & 15;
  int kq = lane >> 4;            // 0..3
  int fx = fr & 3;

  f32x4 acc[8][4];
  #pragma unroll
  for(int m=0;m<8;m++)
    #pragma unroll
    for(int n=0;n<4;n++)
      acc[m][n] = (f32x4){0.f,0.f,0.f,0.f};

  #define STAGE32(buf, kt) { \
    char* aB = (char*)&smem[buf][0][0]; \
    char* bB = (char*)&smem[buf][1][0]; \
    _Pragma("unroll") \
    for(int j=0;j<2;j++){ \
      int c = j*512 + tid; \
      async16(aB + c*16, Ap + (long)(row0+srow[j])*K + (kt) + goff[j]); \
      async16(bB + c*16, Bp + (long)(col0+srow[j])*K + (kt) + goff[j]); \
    } }

  int NT = K >> 5;               // K/32 tiles
  STAGE32(0, 0)
  STAGE32(1, 32)
  int sA = (kq ^ fx) * 8;
  for(int t=0; t<NT; ++t){
    int cur = t & 3;
    if(t+2 < NT){
      STAGE32((t+2)&3, (t+2)*32)
      asm volatile("s_waitcnt vmcnt(8)" ::: "memory");   // tile t's 4 loads done; 8 newer in flight
    } else if(t+1 < NT){
      asm volatile("s_waitcnt vmcnt(4)" ::: "memory");
    } else {
      asm volatile("s_waitcnt vmcnt(0)" ::: "memory");
    }
    __builtin_amdgcn_s_barrier();
    __builtin_amdgcn_sched_barrier(0);
    const short* As = &smem[cur][0][0];
    const short* Bs = &smem[cur][1][0];
    __builtin_amdgcn_s_setprio(1);
    bf16x8 av[8], bv[4];
    #pragma unroll
    for(int m=0;m<8;m++)
      av[m] = *reinterpret_cast<const bf16x8*>(As + (wr + m*16 + fr)*32 + sA);
    #pragma unroll
    for(int n=0;n<4;n++)
      bv[n] = *reinterpret_cast<const bf16x8*>(Bs + (wc + n*16 + fr)*32 + sA);
    #pragma unroll
    for(int m=0;m<8;m++)
      #pragma unroll
      for(int n=0;n<4;n++)
        acc[m][n] = __builtin_amdgcn_mfma_f32_16x16x32_bf16(av[m], bv[n], acc[m][n], 0, 0, 0);
    __builtin_amdgcn_s_setprio(0);
    __builtin_amdgcn_sched_barrier(0);
  }
  #undef STAGE32

  int rr = (lane >> 4) << 2;
  int cc = lane & 15;
  #pragma unroll
  for(int m=0;m<8;m++){
    #pragma unroll
    for(int n=0;n<4;n++){
      int col = col0 + wc + n*16 + cc;
      #pragma unroll
      for(int i=0;i<4;i++){
        long idx = (long)(row0 + wr + m*16 + rr + i)*ldc + col;
        if(MODE==3) ((unsigned short*)Cv)[idx] = f2bf(acc[m][n][i]);
        else        ((float*)Cv)[idx] += acc[m][n][i];
      }
    }
  }
}

// ---------------- fused conv+silu+xproj (MFMA phase 2): xz(bf16) -> dtb_raw [BT,32](f32) ----------------
__global__ __launch_bounds__(256) void xproj_kernel(const unsigned short* __restrict__ xz,
      const float* __restrict__ cw, const unsigned short* __restrict__ wbf,
      float* __restrict__ dtb){
  __shared__ unsigned short xcs[16][DI+8];   // 49,408 B
  __shared__ float pdt[4][16][32];           // 8,192 B partials
  int blk = blockIdx.x;
  int b  = blk >> 7;
  int t0 = (blk & 127) << 4;
  int tid = threadIdx.x;
  long base = ((long)b*SEQ + t0)*(2*DI);
  if(tid < 192){
    int d0 = tid*8;
    float cc0[8], cc1[8], cc2[8], cc3[8];
    #pragma unroll
    for(int j=0;j<8;j++){
      cc0[j]=cw[(d0+j)*4+0]; cc1[j]=cw[(d0+j)*4+1];
      cc2[j]=cw[(d0+j)*4+2]; cc3[j]=cw[(d0+j)*4+3];
    }
    float wm3[8], wm2[8], wm1[8];
    #pragma unroll
    for(int j=0;j<8;j++){ wm3[j]=0.f; wm2[j]=0.f; wm1[j]=0.f; }
    if(t0>0){
      bf16x8 v3 = *reinterpret_cast<const bf16x8*>(xz + base - 3*(2*DI) + d0);
      bf16x8 v2 = *reinterpret_cast<const bf16x8*>(xz + base - 2*(2*DI) + d0);
      bf16x8 v1 = *reinterpret_cast<const bf16x8*>(xz + base - 1*(2*DI) + d0);
      #pragma unroll
      for(int j=0;j<8;j++){
        wm3[j]=bf2f((unsigned short)v3[j]);
        wm2[j]=bf2f((unsigned short)v2[j]);
        wm1[j]=bf2f((unsigned short)v1[j]);
      }
    }
    for(int tt=0; tt<16; tt++){
      bf16x8 vt = *reinterpret_cast<const bf16x8*>(xz + base + (long)tt*(2*DI) + d0);
      bf16x8 o;
      #pragma unroll
      for(int j=0;j<8;j++){
        float wt = bf2f((unsigned short)vt[j]);
        float u  = cc0[j]*wm3[j] + cc1[j]*wm2[j] + cc2[j]*wm1[j] + cc3[j]*wt;
        o[j] = (short)f2bf(siluf(u));
        wm3[j]=wm2[j]; wm2[j]=wm1[j]; wm1[j]=wt;
      }
      *reinterpret_cast<bf16x8*>(&xcs[tt][d0]) = o;
    }
  }
  __syncthreads();
  int wid = tid >> 6, lane = tid & 63;
  int fr = lane & 15, kq = lane >> 4;
  f32x4 a0 = (f32x4){0.f,0.f,0.f,0.f};
  f32x4 a1 = (f32x4){0.f,0.f,0.f,0.f};
  const unsigned short* w0 = wbf + (long)fr*DI;
  const unsigned short* w1 = wbf + (long)(16+fr)*DI;
  int kbase = wid*384 + kq*8;
  #pragma unroll
  for(int ks=0; ks<12; ks++){
    int k = kbase + ks*32;
    bf16x8 av = *reinterpret_cast<const bf16x8*>(&xcs[fr][k]);
    bf16x8 b0 = *reinterpret_cast<const bf16x8*>(w0 + k);
    bf16x8 b1 = *reinterpret_cast<const bf16x8*>(w1 + k);
    a0 = __builtin_amdgcn_mfma_f32_16x16x32_bf16(av, b0, a0, 0, 0, 0);
    a1 = __builtin_amdgcn_mfma_f32_16x16x32_bf16(av, b1, a1, 0, 0, 0);
  }
  int rr = kq << 2;
  #pragma unroll
  for(int i=0;i<4;i++){
    pdt[wid][rr+i][fr]      = a0[i];
    pdt[wid][rr+i][16+fr]   = a1[i];
  }
  __syncthreads();
  for(int e = tid; e < 512; e += 256){
    int r = e >> 5, s = e & 31;
    float v = pdt[0][r][s] + pdt[1][r][s] + pdt[2][r][s] + pdt[3][r][s];
    dtb[((long)b*SEQ + t0 + r)*32 + s] = v;
  }
}

// ---------------- scanAY with MFMA-precomputed da/ba ----------------
__global__ __launch_bounds__(256) void scanAY_mfma_kernel(const unsigned short* __restrict__ xz,
      const float* __restrict__ dtb, const float* __restrict__ cw,
      const unsigned short* __restrict__ wcomb,
      const float* __restrict__ dtbias_g, const float* __restrict__ dp_g,
      float2* __restrict__ chunk, unsigned short* __restrict__ y0s,
      unsigned short* __restrict__ as_s){
  __shared__ unsigned short abuf[64][32];          // 4 KiB
  __shared__ unsigned short dab[64*256*2];         // 64 KiB
  int c = blockIdx.x, db = blockIdx.y, b = blockIdx.z;
  int tid = threadIdx.x;
  int t0 = c*TC;
  {
    const float4* src = reinterpret_cast<const float4*>(dtb + ((long)b*SEQ + t0)*32);
    float4 v0 = src[tid*2], v1 = src[tid*2+1];
    bf16x8 o;
    o[0]=(short)f2bf(v0.x); o[1]=(short)f2bf(v0.y); o[2]=(short)f2bf(v0.z); o[3]=(short)f2bf(v0.w);
    o[4]=(short)f2bf(v1.x); o[5]=(short)f2bf(v1.y); o[6]=(short)f2bf(v1.z); o[7]=(short)f2bf(v1.w);
    *reinterpret_cast<bf16x8*>(&abuf[tid>>2][(tid&3)*8]) = o;
  }
  __syncthreads();
  {
    int w = tid >> 6, lane = tid & 63;
    int fr = lane & 15, kq = lane >> 4;
    bf16x8 zero = {0,0,0,0,0,0,0,0};
    bf16x8 bq[4], bp[4];
    #pragma unroll
    for(int nt=0; nt<4; nt++){
      int dcol = db*256 + w*64 + nt*16 + fr;
      bf16x8 wv = *reinterpret_cast<const bf16x8*>(wcomb + (long)dcol*32 + kq*8);
      bq[nt] = (kq<2) ? wv : zero;
      bp[nt] = (kq<2) ? zero : wv;
    }
    #pragma unroll
    for(int mt=0; mt<4; mt++){
      bf16x8 av = *reinterpret_cast<const bf16x8*>(&abuf[mt*16 + fr][kq*8]);
      #pragma unroll
      for(int nt=0; nt<4; nt++){
        f32x4 aq = __builtin_amdgcn_mfma_f32_16x16x32_bf16(av, bq[nt], (f32x4){0.f,0.f,0.f,0.f}, 0,0,0);
        f32x4 ap = __builtin_amdgcn_mfma_f32_16x16x32_bf16(av, bp[nt], (f32x4){0.f,0.f,0.f,0.f}, 0,0,0);
        int dl = w*64 + nt*16 + fr;
        #pragma unroll
        for(int i=0;i<4;i++){
          int t = mt*16 + kq*4 + i;
          unsigned int pack = (unsigned int)f2bf(aq[i]) | (((unsigned int)f2bf(ap[i]))<<16);
          *reinterpret_cast<unsigned int*>(&dab[(t*256 + dl)*2]) = pack;
        }
      }
    }
  }
  int d = db*256 + tid;
  float c0=cw[d*4],c1=cw[d*4+1],c2=cw[d*4+2],c3=cw[d*4+3];
  float bias = dtbias_g[d];
  float dp = dp_g[d];
  asm volatile("" : "+v"(c0),"+v"(c1),"+v"(c2),"+v"(c3),"+v"(bias),"+v"(dp));
  long base = ((long)b*SEQ + t0)*(2*DI) + d;
  float wm3 = (t0>0) ? bf2f(xz[base - 3*(2*DI)]) : 0.f;
  float wm2 = (t0>0) ? bf2f(xz[base - 2*(2*DI)]) : 0.f;
  float wm1 = (t0>0) ? bf2f(xz[base - 1*(2*DI)]) : 0.f;
  const unsigned short* xp = xz + base;
  long sidx = ((long)b*SEQ + t0)*DI + d;
  unsigned short* yp = y0s + sidx;
  unsigned short* ap2 = as_s + sidx;
  __syncthreads();
  float h = 0.f, P = 1.f;
  const unsigned int* dab32 = reinterpret_cast<const unsigned int*>(dab);
  for(int g=0; g<TC/8; g++){
    unsigned short xv[8];
    #pragma unroll
    for(int j=0;j<8;j++){ xv[j] = xp[(long)j*2*DI]; }
    xp += 8L*2*DI;
    #pragma unroll
    for(int j=0;j<8;j++){
      float wt = bf2f(xv[j]);
      float u = siluf(fmaf(c3,wt, fmaf(c2,wm1, fmaf(c1,wm2, c0*wm3))));
      wm3=wm2; wm2=wm1; wm1=wt;
      unsigned int pk = dab32[(g*8+j)*256 + tid];
      float da = bias + bf2f((unsigned short)(pk & 0xffffu));
      float ba = bf2f((unsigned short)(pk >> 16));
      float delta = fminf(fmaxf(fast_softplus(da), 1e-4f), 1.0f);
      float a = 1.0f - delta;
      h = fmaf(h, a, u*ba);
      P *= a;
      yp[(long)j*DI]  = f2bf(fmaf(dp, u, h));
      ap2[(long)j*DI] = f2bf(P);
    }
    yp += 8L*DI; ap2 += 8L*DI;
  }
  chunk[((long)b*DI + d)*NCHUNK + c] = make_float2(P, h);
}

// ---------------- scanAY (fallback) ----------------
__global__ __launch_bounds__(256) void scanAY_kernel(const unsigned short* __restrict__ xz,
      const float* __restrict__ dtb, const float* __restrict__ cw,
      const float* __restrict__ dtw_g, const float* __restrict__ dtbias_g,
      const float* __restrict__ bpw_g, const float* __restrict__ dp_g,
      float2* __restrict__ chunk, unsigned short* __restrict__ y,
      unsigned short* __restrict__ asz_s){
  __shared__ float dsb[TC*32];
  int c = blockIdx.x, db = blockIdx.y, b = blockIdx.z;
  int d = db*256 + threadIdx.x;
  int t0 = c*TC;
  {
    const float4* src = reinterpret_cast<const float4*>(dtb + ((long)b*SEQ + t0)*32);
    float4* dst = reinterpret_cast<float4*>(dsb);
    dst[threadIdx.x]       = src[threadIdx.x];
    dst[threadIdx.x + 256] = src[threadIdx.x + 256];
  }
  float c0=cw[d*4],c1=cw[d*4+1],c2=cw[d*4+2],c3=cw[d*4+3];
  f32x4 wq0 = *reinterpret_cast<const f32x4*>(dtw_g + d*16 + 0);
  f32x4 wq1 = *reinterpret_cast<const f32x4*>(dtw_g + d*16 + 4);
  f32x4 wq2 = *reinterpret_cast<const f32x4*>(dtw_g + d*16 + 8);
  f32x4 wq3 = *reinterpret_cast<const f32x4*>(dtw_g + d*16 + 12);
  f32x4 wp0 = *reinterpret_cast<const f32x4*>(bpw_g + d*16 + 0);
  f32x4 wp1 = *reinterpret_cast<const f32x4*>(bpw_g + d*16 + 4);
  f32x4 wp2 = *reinterpret_cast<const f32x4*>(bpw_g + d*16 + 8);
  f32x4 wp3 = *reinterpret_cast<const f32x4*>(bpw_g + d*16 + 12);
  float bias = dtbias_g[d];
  float dp = dp_g[d];
  asm volatile("" : "+v"(wq0),"+v"(wq1),"+v"(wq2),"+v"(wq3),
                    "+v"(wp0),"+v"(wp1),"+v"(wp2),"+v"(wp3),
                    "+v"(c0),"+v"(c1),"+v"(c2),"+v"(c3),"+v"(bias),"+v"(dp));
  long base = ((long)b*SEQ + t0)*(2*DI) + d;
  float wm3 = (t0>0) ? bf2f(xz[base - 3*(2*DI)]) : 0.f;
  float wm2 = (t0>0) ? bf2f(xz[base - 2*(2*DI)]) : 0.f;
  float wm1 = (t0>0) ? bf2f(xz[base - 1*(2*DI)]) : 0.f;
  const unsigned short* xp = xz + base;
  const unsigned short* zp = xz + base + DI;
  long sidx = ((long)b*SEQ + t0)*DI + d;
  unsigned short* yp = y + sidx;
  unsigned short* ap = asz_s + sidx;
  __syncthreads();
  float h = 0.f, P = 1.f;
  for(int g=0; g<TC/8; g++){
    unsigned short xv[8], zv[8];
    #pragma unroll
    for(int j=0;j<8;j++){ xv[j] = xp[(long)j*2*DI]; zv[j] = zp[(long)j*2*DI]; }
    xp += 8L*2*DI; zp += 8L*2*DI;
    const float* rp = dsb + g*8*32;
    #pragma unroll
    for(int j=0;j<8;j++){
      float wt = bf2f(xv[j]);
      float u = siluf(fmaf(c3,wt, fmaf(c2,wm1, fmaf(c1,wm2, c0*wm3))));
      wm3=wm2; wm2=wm1; wm1=wt;
      const f32x4* row = reinterpret_cast<const f32x4*>(rp + j*32);
      float da = bias + dot4(row[0],wq0) + dot4(row[1],wq1) + dot4(row[2],wq2) + dot4(row[3],wq3);
      float ba =        dot4(row[4],wp0) + dot4(row[5],wp1) + dot4(row[6],wp2) + dot4(row[7],wp3);
      float delta = fminf(fmaxf(fast_softplus(da), 1e-4f), 1.0f);
      float a = 1.0f - delta;
      h = fmaf(h, a, u*ba);
      P *= a;
      float sz = siluf(bf2f(zv[j]));
      yp[(long)j*DI] = f2bf(fmaf(dp, u, h) * sz);
      ap[(long)j*DI] = f2bf(P * sz);
    }
    yp += 8L*DI; ap += 8L*DI;
  }
  chunk[((long)b*DI + d)*NCHUNK + c] = make_float2(P, h);
}

// ---------------- h0 table: prefix-combine chunk summaries ----------------
__global__ __launch_bounds__(256) void h0_kernel(const float2* __restrict__ chunk,
                                                 float* __restrict__ h0tab){
  int idx = blockIdx.x*256 + threadIdx.x;
  int b = idx / DI, d = idx - b*DI;
  const float2* cb = chunk + ((long)b*DI + d)*NCHUNK;
  float h0 = 0.f;
  for(int c=0; c<NCHUNK; c++){
    h0tab[((long)b*NCHUNK + c)*DI + d] = h0;
    float2 ps = cb[c];
    h0 = fmaf(ps.x, h0, ps.y);
  }
}

// ---------------- fixup_z: y = (y0 + h0*A) * silu(z) ----------------
__global__ __launch_bounds__(256) void fixup_z_kernel(const unsigned short* __restrict__ as_s,
      const float* __restrict__ h0tab, const unsigned short* __restrict__ xz,
      unsigned short* __restrict__ y){
  int i = (blockIdx.x*256 + threadIdx.x)*8;
  int bt = i / DI;
  int d  = i - bt*DI;
  int b  = bt >> 11;
  int c  = (bt & 2047) >> 6;
  const float* hp = h0tab + ((long)b*NCHUNK + c)*DI + d;
  f32x4 h0a = *reinterpret_cast<const f32x4*>(hp);
  f32x4 h0b = *reinterpret_cast<const f32x4*>(hp + 4);
  bf16x8 yv = *reinterpret_cast<const bf16x8*>(y + i);
  bf16x8 av = *reinterpret_cast<const bf16x8*>(as_s + i);
  bf16x8 zv = *reinterpret_cast<const bf16x8*>(xz + (long)bt*(2*DI) + DI + d);
  bf16x8 o;
  #pragma unroll
  for(int j=0;j<8;j++){
    float h0 = (j<4) ? h0a[j] : h0b[j-4];
    float v = fmaf(h0, bf2f((unsigned short)av[j]), bf2f((unsigned short)yv[j]));
    o[j] = (short)f2bf(v * siluf(bf2f((unsigned short)zv[j])));
  }
  *reinterpret_cast<bf16x8*>(y + i) = o;
}

// ---------------- fixup (fallback): y += h0 * asz ----------------
__global__ __launch_bounds__(256) void fixup_kernel(const unsigned short* __restrict__ asz_s,
      const float* __restrict__ h0tab, unsigned short* __restrict__ y){
  int i = (blockIdx.x*256 + threadIdx.x)*8;
  int bt = i / DI;
  int d  = i - bt*DI;
  int b  = bt >> 11;
  int c  = (bt & 2047) >> 6;
  const float* hp = h0tab + ((long)b*NCHUNK + c)*DI + d;
  f32x4 h0a = *reinterpret_cast<const f32x4*>(hp);
  f32x4 h0b = *reinterpret_cast<const f32x4*>(hp + 4);
  bf16x8 yv = *reinterpret_cast<const bf16x8*>(y + i);
  bf16x8 av = *reinterpret_cast<const bf16x8*>(asz_s + i);
  bf16x8 o;
  #pragma unroll
  for(int j=0;j<8;j++){
    float h0 = (j<4) ? h0a[j] : h0b[j-4];
    o[j] = (short)f2bf(fmaf(h0, bf2f((unsigned short)av[j]), bf2f((unsigned short)yv[j])));
  }
  *reinterpret_cast<bf16x8*>(y + i) = o;
}

// ---------------- launch ----------------
extern "C" void kernel_launch(void* const* d_in, const int* in_sizes, int n_in,
                              void* d_out, int out_size, void* d_ws, size_t ws_size,
                              hipStream_t stream){
  const int*   tokens  = (const int*)  d_in[0];
  const int*   emotion = (const int*)  d_in[1];
  const int*   style   = (const int*)  d_in[2];
  const int*   keysig  = (const int*)  d_in[3];
  const int*   modei   = (const int*)  d_in[4];
  const float* bpm     = (const float*)d_in[5];
  const float* tok_emb = (const float*)d_in[6];
  const float* emo_emb = (const float*)d_in[7];
  const float* sty_emb = (const float*)d_in[8];
  const float* key_emb = (const float*)d_in[9];
  const float* mode_emb= (const float*)d_in[10];
  const float* bpm_w   = (const float*)d_in[11];
  const float* bpm_b   = (const float*)d_in[12];
  const float* cond_w  = (const float*)d_in[13];
  const float* cond_b  = (const float*)d_in[14];
  const float* pos_emb = (const float*)d_in[15];
  const float* ln_g    = (const float*)d_in[16];
  const float* ln_b    = (const float*)d_in[17];
  const float* in_w    = (const float*)d_in[18];
  const float* conv_w  = (const float*)d_in[19];
  const float* xproj_w = (const float*)d_in[20];
  const float* dt_w    = (const float*)d_in[21];
  const float* dt_b    = (const float*)d_in[22];
  const float* bproj_w = (const float*)d_in[23];
  const float* d_param = (const float*)d_in[24];
  const float* out_w   = (const float*)d_in[25];
  const float* final_g = (const float*)d_in[26];
  const float* final_b = (const float*)d_in[27];
  const float* head_w  = (const float*)d_in[28];
  const float* head_b  = (const float*)d_in[29];

  // workspace layout: base 215,244,800 B; +h0tab +asz -> 267,149,312; +wcomb -> 267,935,744
  char* ws = (char*)d_ws;
  float*          x       = (float*)(ws + 0L);                    //  50,331,648
  unsigned short* hy      = (unsigned short*)(ws + 50331648L);    //  50,331,648
  unsigned short* xz      = (unsigned short*)(ws + 100663296L);   // 100,663,296
  float*          dtbuf   = (float*)(ws + 201326592L);            //   2,097,152
  float2*         chunk   = (float2*)(ws + 203423744L);           //   3,145,728
  float*          condv   = (float*)(ws + 206569472L);            //      24,576
  unsigned short* inwb    = (unsigned short*)(ws + 206594048L);   //   4,718,592
  unsigned short* outwb   = (unsigned short*)(ws + 211312640L);   //   2,359,296
  unsigned short* headwb  = (unsigned short*)(ws + 213671936L);   //     786,432
  unsigned short* wbf_all = (unsigned short*)(ws + 214458368L);   //     786,432 -> 215,244,800
  float*          h0tab   = (float*)(ws + 215244800L);            //   1,572,864
  unsigned short* asz_s   = (unsigned short*)(ws + 216817664L);   //  50,331,648 -> 267,149,312
  unsigned short* wcombb  = (unsigned short*)(ws + 267149312L);   //     786,432 -> 267,935,744

  const bool use_mfma = (ws_size >= 267935744UL);

  unsigned short* h_bf = hy;        // [BT, DM]
  unsigned short* y_bf = hy;        // [BT, DI]
  unsigned short* xfin = hy;        // [BT, DM]

  cvt_bf16_kernel<<<128,256,0,stream>>>((const float4*)head_w,(ushort4*)headwb, NVOCAB*DM/4);
  cvt_bf16_kernel<<<384,256,0,stream>>>((const float4*)xproj_w,(ushort4*)wbf_all, NL*32*DI/4);
  if(use_mfma)
    wcomb_kernel<<<NL*DI*32/256,256,0,stream>>>(dt_w, bproj_w, wcombb);
  cond_kernel<<<dim3(DM/4,8),256,0,stream>>>(emotion, style, keysig, modei, bpm, emo_emb, sty_emb,
        key_emb, mode_emb, bpm_w, bpm_b, cond_w, cond_b, condv);
  embed_kernel<<<BT,192,0,stream>>>(tokens, tok_emb, condv, pos_emb, x);

  for(int l=0; l<NL; l++){
    cvt_bf16_kernel<<<1024,256,0,stream>>>((const float4*)(in_w  + (long)l*2*DI*DM), (ushort4*)inwb,  2*DI*DM/4);
    cvt_bf16_kernel<<<512, 256,0,stream>>>((const float4*)(out_w + (long)l*DM*DI),   (ushort4*)outwb, DM*DI/4);
    ln_bf16_kernel<<<BT/4,256,0,stream>>>(x, ln_g + l*DM, ln_b + l*DM, h_bf);
    gemm256<3><<<dim3(2*DI/256, BT/256),512,0,stream>>>(h_bf, inwb, xz, DM, 2*DI);
    xproj_kernel<<<BT/16,256,0,stream>>>(xz, conv_w + l*DI*4, wbf_all + (long)l*32*DI, dtbuf);
    if(use_mfma){
      scanAY_mfma_kernel<<<dim3(NCHUNK,6,BATCH),256,0,stream>>>(xz, dtbuf, conv_w + l*DI*4,
            wcombb + (long)l*DI*32, dt_b + l*DI, d_param + l*DI, chunk, y_bf, asz_s);
      h0_kernel<<<48,256,0,stream>>>(chunk, h0tab);
      fixup_z_kernel<<<BT*DI/(256*8),256,0,stream>>>(asz_s, h0tab, xz, y_bf);
    } else {
      scanAY_kernel<<<dim3(NCHUNK,6,BATCH),256,0,stream>>>(xz, dtbuf, conv_w + l*DI*4,
            dt_w + l*DI*DS, dt_b + l*DI, bproj_w + l*DI*DS, d_param + l*DI, chunk, y_bf, asz_s);
      h0_kernel<<<48,256,0,stream>>>(chunk, h0tab);
      fixup_kernel<<<BT*DI/(256*8),256,0,stream>>>(asz_s, h0tab, y_bf);
    }
    gemm_lds<1><<<dim3(DM/128, BT/128),256,0,stream>>>(y_bf, outwb, x, nullptr, DI, DM);
  }
  ln_bf16_kernel<<<BT/4,256,0,stream>>>(x, final_g, final_b, xfin);
  gemm_lds<2><<<dim3(NVOCAB/128, BT/128),256,0,stream>>>(xfin, headwb, d_out, head_b, DM, NVOCAB);
}

// Round 17
// 2261.345 us; speedup vs baseline: 1.0209x; 1.0209x over previous
//
#include <hip/hip_runtime.h>
#include <cstdint>

#define BATCH 8
#define SEQ   2048
#define DM    768
#define DI    1536
#define DS    16
#define NL    8
#define NVOCAB 512
#define BT    (BATCH*SEQ)      // 16384
#define NCHUNK 32
#define TC    (SEQ/NCHUNK)     // 64

typedef __attribute__((ext_vector_type(8))) short bf16x8;
typedef __attribute__((ext_vector_type(4))) float f32x4;

__device__ __forceinline__ unsigned short f2bf(float f){
  unsigned int u = __float_as_uint(f);
  u += 0x7fffu + ((u >> 16) & 1u);
  return (unsigned short)(u >> 16);
}
__device__ __forceinline__ float bf2f(unsigned short s){
  return __uint_as_float(((unsigned int)s) << 16);
}
__device__ __forceinline__ float sigm(float x){ return 1.0f/(1.0f + __expf(-x)); }
__device__ __forceinline__ float siluf(float x){ return x * sigm(x); }
__device__ __forceinline__ float fast_softplus(float x){
  return (x > 15.0f) ? x : __logf(1.0f + __expf(x));
}
__device__ __forceinline__ void async16(void* l, const void* g){
  __builtin_amdgcn_global_load_lds(
      (const __attribute__((address_space(1))) unsigned int*)g,
      (__attribute__((address_space(3))) unsigned int*)l, 16, 0, 0);
}
__device__ __forceinline__ float dot4(f32x4 a, f32x4 b){
  return fmaf(a[0],b[0], fmaf(a[1],b[1], fmaf(a[2],b[2], a[3]*b[3])));
}

// ---------------- weight conversion ----------------
__global__ void cvt_bf16_kernel(const float4* __restrict__ in, ushort4* __restrict__ out, int n4){
  int i = blockIdx.x*256 + threadIdx.x;
  int stride = gridDim.x*256;
  for(; i<n4; i+=stride){
    float4 v = in[i];
    ushort4 o; o.x=f2bf(v.x); o.y=f2bf(v.y); o.z=f2bf(v.z); o.w=f2bf(v.w);
    out[i]=o;
  }
}

// merged two-buffer conversion (one launch per layer)
__global__ void cvt2_bf16_kernel(const float4* __restrict__ a, ushort4* __restrict__ oa, int na4,
                                 const float4* __restrict__ b, ushort4* __restrict__ ob, int nb4){
  int i = blockIdx.x*256 + threadIdx.x;
  int stride = gridDim.x*256;
  int tot = na4 + nb4;
  for(; i<tot; i+=stride){
    float4 v; int isA = (i < na4); int j = isA ? i : i - na4;
    v = isA ? a[j] : b[j];
    ushort4 o; o.x=f2bf(v.x); o.y=f2bf(v.y); o.z=f2bf(v.z); o.w=f2bf(v.w);
    if(isA) oa[j] = o; else ob[j] = o;
  }
}

// wcomb[l][d][k]: k<16 -> dt_w[l][d][k], else bproj_w[l][d][k-16]  (bf16)
__global__ void wcomb_kernel(const float* __restrict__ dt_w, const float* __restrict__ bproj_w,
                             unsigned short* __restrict__ out){
  int idx = blockIdx.x*256 + threadIdx.x;   // NL*DI*32 = 393216
  int k = idx & 31, ld = idx >> 5;
  float v = (k < 16) ? dt_w[(long)ld*16 + k] : bproj_w[(long)ld*16 + (k-16)];
  out[idx] = f2bf(v);
}

// ---------------- conditioning (float4, 1 wave per dm, grid (DM/4, BATCH)) ----------------
__global__ __launch_bounds__(256) void cond_kernel(const int* __restrict__ emotion,
    const int* __restrict__ style, const int* __restrict__ keysig, const int* __restrict__ modei,
    const float* __restrict__ bpm, const float* __restrict__ emo_emb, const float* __restrict__ sty_emb,
    const float* __restrict__ key_emb, const float* __restrict__ mode_emb,
    const float* __restrict__ bpm_w, const float* __restrict__ bpm_b,
    const float* __restrict__ cond_w, const float* __restrict__ cond_b,
    float* __restrict__ cond_out){
  int b = blockIdx.y;
  int tid = threadIdx.x;
  __shared__ float vec[5*DM];        // 3840 f32 = 960 float4
  int e = emotion[b], st = style[b], ks = keysig[b], md = modei[b];
  float bp = bpm[b];
  for(int j=tid; j<960; j+=256){
    int seg = j/192, o4 = j - seg*192;
    float4 v;
    if(seg==0)      v = reinterpret_cast<const float4*>(emo_emb + (long)e*DM)[o4];
    else if(seg==1) v = reinterpret_cast<const float4*>(sty_emb + (long)st*DM)[o4];
    else if(seg==2) v = reinterpret_cast<const float4*>(key_emb + (long)ks*DM)[o4];
    else if(seg==3) v = reinterpret_cast<const float4*>(mode_emb + (long)md*DM)[o4];
    else {
      float4 w = reinterpret_cast<const float4*>(bpm_w)[o4];
      float4 bb = reinterpret_cast<const float4*>(bpm_b)[o4];
      v = make_float4(fmaf(bp,w.x,bb.x), fmaf(bp,w.y,bb.y), fmaf(bp,w.z,bb.z), fmaf(bp,w.w,bb.w));
    }
    reinterpret_cast<float4*>(vec)[j] = v;
  }
  __syncthreads();
  int wid = tid>>6, lane = tid&63;
  int dm = blockIdx.x*4 + wid;
  const float4* w4 = reinterpret_cast<const float4*>(cond_w + (long)dm*(5*DM));
  const float4* v4 = reinterpret_cast<const float4*>(vec);
  float acc = 0.f;
  #pragma unroll 5
  for(int j=lane; j<960; j+=64){
    float4 w = w4[j], v = v4[j];
    acc = fmaf(w.x,v.x, fmaf(w.y,v.y, fmaf(w.z,v.z, fmaf(w.w,v.w, acc))));
  }
  #pragma unroll
  for(int off=32; off>0; off>>=1) acc += __shfl_xor(acc, off);
  if(lane==0) cond_out[b*DM + dm] = acc + cond_b[dm];
}

// x = tok_emb[tokens] + cond + pos_emb
__global__ void embed_kernel(const int* __restrict__ tokens, const float* __restrict__ tok_emb,
    const float* __restrict__ cond, const float* __restrict__ pos_emb, float* __restrict__ x){
  int bt = blockIdx.x;
  int b = bt >> 11, t = bt & 2047;
  int tok = tokens[bt];
  const float4* te = reinterpret_cast<const float4*>(tok_emb + (long)tok*DM);
  const float4* ce = reinterpret_cast<const float4*>(cond + (long)b*DM);
  const float4* pe = reinterpret_cast<const float4*>(pos_emb + (long)t*DM);
  float4* xo = reinterpret_cast<float4*>(x + (long)bt*DM);
  int i = threadIdx.x;  // 0..191
  float4 a = te[i], c = ce[i], p = pe[i];
  xo[i] = make_float4(a.x+c.x+p.x, a.y+c.y+p.y, a.z+c.z+p.z, a.w+c.w+p.w);
}

// ---------------- layernorm -> bf16 ----------------
__global__ __launch_bounds__(256) void ln_bf16_kernel(const float* __restrict__ x,
                     const float* __restrict__ g, const float* __restrict__ bta,
                     unsigned short* __restrict__ out){
  int row  = blockIdx.x*4 + (threadIdx.x >> 6);
  int lane = threadIdx.x & 63;
  const float* xr = x + (long)row*DM;
  float4 v[3];
  float sum=0.f, sq=0.f;
  #pragma unroll
  for(int i=0;i<3;i++){
    v[i] = *reinterpret_cast<const float4*>(xr + i*256 + lane*4);
    sum += v[i].x + v[i].y + v[i].z + v[i].w;
    sq  += v[i].x*v[i].x + v[i].y*v[i].y + v[i].z*v[i].z + v[i].w*v[i].w;
  }
  #pragma unroll
  for(int off=32; off>0; off>>=1){
    sum += __shfl_xor(sum, off);
    sq  += __shfl_xor(sq , off);
  }
  float mu  = sum * (1.0f/DM);
  float var = sq  * (1.0f/DM) - mu*mu;
  float rs  = rsqrtf(var + 1e-5f);
  unsigned short* orow = out + (long)row*DM;
  #pragma unroll
  for(int i=0;i<3;i++){
    int d = i*256 + lane*4;
    float4 gg = *reinterpret_cast<const float4*>(g + d);
    float4 bb = *reinterpret_cast<const float4*>(bta + d);
    ushort4 o;
    o.x = f2bf((v[i].x - mu)*rs*gg.x + bb.x);
    o.y = f2bf((v[i].y - mu)*rs*gg.y + bb.y);
    o.z = f2bf((v[i].z - mu)*rs*gg.z + bb.z);
    o.w = f2bf((v[i].w - mu)*rs*gg.w + bb.w);
    *reinterpret_cast<ushort4*>(orow + d) = o;
  }
}

// ---------------- LDS-staged GEMM, BK=64 + T2 XOR swizzle (round-11 exact): C = A * B^T
template<int MODE>
__global__ __launch_bounds__(256) void gemm_lds(const unsigned short* __restrict__ A,
                                               const unsigned short* __restrict__ B,
                                               void* __restrict__ Cv,
                                               const float* __restrict__ bias,
                                               int K, int ldc){
  __shared__ short As[128*64];   // 16 KiB
  __shared__ short Bs[128*64];   // 16 KiB
  const short* Ap = (const short*)A;
  const short* Bp = (const short*)B;
  int tid  = threadIdx.x;
  int lane = tid & 63;
  int wid  = tid >> 6;

  int nbx = gridDim.x;
  int id  = blockIdx.y*nbx + blockIdx.x;
  int q   = (nbx*gridDim.y) >> 3;
  int swz = (id & 7)*q + (id >> 3);
  int bx  = swz % nbx, by = swz / nbx;
  int row0 = by*128;
  int col0 = bx*128;

  int srow[4], goff[4];
  #pragma unroll
  for(int j=0;j<4;j++){
    int c = j*256 + tid;
    int row = c>>3, s = c&7;
    srow[j] = row;
    goff[j] = (s ^ (row&7))*8;
  }

  int wr = (wid>>1)*64;
  int wc = (wid&1)*64;
  int fr = lane & 15;
  int kq = lane >> 4;
  int fx = fr & 7;

  f32x4 acc[4][4];
  #pragma unroll
  for(int m=0;m<4;m++)
    #pragma unroll
    for(int n=0;n<4;n++)
      acc[m][n] = (f32x4){0.f,0.f,0.f,0.f};

  for(int kt=0; kt<K; kt+=64){
    #pragma unroll
    for(int j=0;j<4;j++){
      int c = j*256 + tid;
      async16((char*)As + c*16, Ap + (long)(row0+srow[j])*K + kt + goff[j]);
      async16((char*)Bs + c*16, Bp + (long)(col0+srow[j])*K + kt + goff[j]);
    }
    __syncthreads();
    #pragma unroll
    for(int ks=0; ks<2; ks++){
      int sA = ((ks*4 + kq) ^ fx) * 8;
      bf16x8 av[4], bv[4];
      #pragma unroll
      for(int m=0;m<4;m++)
        av[m] = *reinterpret_cast<const bf16x8*>(As + (wr + m*16 + fr)*64 + sA);
      #pragma unroll
      for(int n=0;n<4;n++)
        bv[n] = *reinterpret_cast<const bf16x8*>(Bs + (wc + n*16 + fr)*64 + sA);
      #pragma unroll
      for(int m=0;m<4;m++)
        #pragma unroll
        for(int n=0;n<4;n++)
          acc[m][n] = __builtin_amdgcn_mfma_f32_16x16x32_bf16(av[m], bv[n], acc[m][n], 0, 0, 0);
    }
    __syncthreads();
  }

  int rr = (lane >> 4) << 2;
  int cc = lane & 15;
  #pragma unroll
  for(int m=0;m<4;m++){
    #pragma unroll
    for(int n=0;n<4;n++){
      int col = col0 + wc + n*16 + cc;
      #pragma unroll
      for(int i=0;i<4;i++){
        long idx = (long)(row0 + wr + m*16 + rr + i)*ldc + col;
        float v = acc[m][n][i];
        if(MODE==3)      ((unsigned short*)Cv)[idx] = f2bf(v);
        else if(MODE==1) ((float*)Cv)[idx] += v;
        else if(MODE==2) ((float*)Cv)[idx] = v + bias[col];
        else             ((float*)Cv)[idx] = v;
      }
    }
  }
}

// ---------------- 256x256 GEMM, 8 waves, 128KB dbuf, single-barrier (round-15 exact) ----------------
template<int MODE>
__global__ __launch_bounds__(512) void gemm256(const unsigned short* __restrict__ A,
                                               const unsigned short* __restrict__ B,
                                               void* __restrict__ Cv,
                                               int K, int ldc){
  __shared__ short smem[2][2][256*64];   // [buf][A|B] : 128 KiB
  const short* Ap = (const short*)A;
  const short* Bp = (const short*)B;
  int tid  = threadIdx.x;        // 0..511
  int lane = tid & 63;
  int wid  = tid >> 6;           // 0..7

  int nbx = gridDim.x;
  int id  = blockIdx.y*nbx + blockIdx.x;
  int q   = (nbx*gridDim.y) >> 3;
  int swz = (id & 7)*q + (id >> 3);
  int bx  = swz % nbx, by = swz / nbx;
  int row0 = by*256;
  int col0 = bx*256;

  int srow[4], goff[4];
  #pragma unroll
  for(int j=0;j<4;j++){
    int c = j*512 + tid;
    int row = c>>3, s = c&7;
    srow[j] = row;
    goff[j] = (s ^ (row&7))*8;
  }

  int wr = (wid>>2)*128;         // wave M-offset (0 or 128)
  int wc = (wid&3)*64;           // wave N-offset (0,64,128,192)
  int fr = lane & 15;
  int kq = lane >> 4;
  int fx = fr & 7;

  f32x4 acc[8][4];
  #pragma unroll
  for(int m=0;m<8;m++)
    #pragma unroll
    for(int n=0;n<4;n++)
      acc[m][n] = (f32x4){0.f,0.f,0.f,0.f};

  #define STAGE256(buf, kt) { \
    char* aB = (char*)&smem[buf][0][0]; \
    char* bB = (char*)&smem[buf][1][0]; \
    _Pragma("unroll") \
    for(int j=0;j<4;j++){ \
      int c = j*512 + tid; \
      async16(aB + c*16, Ap + (long)(row0+srow[j])*K + (kt) + goff[j]); \
      async16(bB + c*16, Bp + (long)(col0+srow[j])*K + (kt) + goff[j]); \
    } }

  int NT = K >> 6;
  STAGE256(0, 0)
  asm volatile("s_waitcnt vmcnt(0)" ::: "memory");
  __builtin_amdgcn_s_barrier();
  for(int t=0; t<NT; ++t){
    int cur = t & 1;
    if(t+1 < NT){
      STAGE256(cur^1, (t+1)*64)
    }
    const short* As = &smem[cur][0][0];
    const short* Bs = &smem[cur][1][0];
    __builtin_amdgcn_s_setprio(1);
    #pragma unroll
    for(int ks=0; ks<2; ks++){
      int sA = ((ks*4 + kq) ^ fx) * 8;
      bf16x8 av[8], bv[4];
      #pragma unroll
      for(int m=0;m<8;m++)
        av[m] = *reinterpret_cast<const bf16x8*>(As + (wr + m*16 + fr)*64 + sA);
      #pragma unroll
      for(int n=0;n<4;n++)
        bv[n] = *reinterpret_cast<const bf16x8*>(Bs + (wc + n*16 + fr)*64 + sA);
      #pragma unroll
      for(int m=0;m<8;m++)
        #pragma unroll
        for(int n=0;n<4;n++)
          acc[m][n] = __builtin_amdgcn_mfma_f32_16x16x32_bf16(av[m], bv[n], acc[m][n], 0, 0, 0);
    }
    __builtin_amdgcn_s_setprio(0);
    __builtin_amdgcn_sched_barrier(0);
    if(t+1 < NT){
      asm volatile("s_waitcnt vmcnt(0)" ::: "memory");   // next tile landed (hidden under MFMA)
    }
    __builtin_amdgcn_s_barrier();
  }
  #undef STAGE256

  int rr = (lane >> 4) << 2;
  int cc = lane & 15;
  #pragma unroll
  for(int m=0;m<8;m++){
    #pragma unroll
    for(int n=0;n<4;n++){
      int col = col0 + wc + n*16 + cc;
      #pragma unroll
      for(int i=0;i<4;i++){
        long idx = (long)(row0 + wr + m*16 + rr + i)*ldc + col;
        if(MODE==3) ((unsigned short*)Cv)[idx] = f2bf(acc[m][n][i]);
        else        ((float*)Cv)[idx] += acc[m][n][i];
      }
    }
  }
}

// ---------------- fused conv+silu+xproj (MFMA phase 2): xz(bf16) -> dtb_raw [BT,32](f32) ----------------
__global__ __launch_bounds__(256) void xproj_kernel(const unsigned short* __restrict__ xz,
      const float* __restrict__ cw, const unsigned short* __restrict__ wbf,
      float* __restrict__ dtb){
  __shared__ unsigned short xcs[16][DI+8];   // 49,408 B
  __shared__ float pdt[4][16][32];           // 8,192 B partials
  int blk = blockIdx.x;
  int b  = blk >> 7;
  int t0 = (blk & 127) << 4;
  int tid = threadIdx.x;
  long base = ((long)b*SEQ + t0)*(2*DI);
  if(tid < 192){
    int d0 = tid*8;
    float cc0[8], cc1[8], cc2[8], cc3[8];
    #pragma unroll
    for(int j=0;j<8;j++){
      cc0[j]=cw[(d0+j)*4+0]; cc1[j]=cw[(d0+j)*4+1];
      cc2[j]=cw[(d0+j)*4+2]; cc3[j]=cw[(d0+j)*4+3];
    }
    float wm3[8], wm2[8], wm1[8];
    #pragma unroll
    for(int j=0;j<8;j++){ wm3[j]=0.f; wm2[j]=0.f; wm1[j]=0.f; }
    if(t0>0){
      bf16x8 v3 = *reinterpret_cast<const bf16x8*>(xz + base - 3*(2*DI) + d0);
      bf16x8 v2 = *reinterpret_cast<const bf16x8*>(xz + base - 2*(2*DI) + d0);
      bf16x8 v1 = *reinterpret_cast<const bf16x8*>(xz + base - 1*(2*DI) + d0);
      #pragma unroll
      for(int j=0;j<8;j++){
        wm3[j]=bf2f((unsigned short)v3[j]);
        wm2[j]=bf2f((unsigned short)v2[j]);
        wm1[j]=bf2f((unsigned short)v1[j]);
      }
    }
    for(int tt=0; tt<16; tt++){
      bf16x8 vt = *reinterpret_cast<const bf16x8*>(xz + base + (long)tt*(2*DI) + d0);
      bf16x8 o;
      #pragma unroll
      for(int j=0;j<8;j++){
        float wt = bf2f((unsigned short)vt[j]);
        float u  = cc0[j]*wm3[j] + cc1[j]*wm2[j] + cc2[j]*wm1[j] + cc3[j]*wt;
        o[j] = (short)f2bf(siluf(u));
        wm3[j]=wm2[j]; wm2[j]=wm1[j]; wm1[j]=wt;
      }
      *reinterpret_cast<bf16x8*>(&xcs[tt][d0]) = o;
    }
  }
  __syncthreads();
  int wid = tid >> 6, lane = tid & 63;
  int fr = lane & 15, kq = lane >> 4;
  f32x4 a0 = (f32x4){0.f,0.f,0.f,0.f};
  f32x4 a1 = (f32x4){0.f,0.f,0.f,0.f};
  const unsigned short* w0 = wbf + (long)fr*DI;
  const unsigned short* w1 = wbf + (long)(16+fr)*DI;
  int kbase = wid*384 + kq*8;
  #pragma unroll
  for(int ks=0; ks<12; ks++){
    int k = kbase + ks*32;
    bf16x8 av = *reinterpret_cast<const bf16x8*>(&xcs[fr][k]);
    bf16x8 b0 = *reinterpret_cast<const bf16x8*>(w0 + k);
    bf16x8 b1 = *reinterpret_cast<const bf16x8*>(w1 + k);
    a0 = __builtin_amdgcn_mfma_f32_16x16x32_bf16(av, b0, a0, 0, 0, 0);
    a1 = __builtin_amdgcn_mfma_f32_16x16x32_bf16(av, b1, a1, 0, 0, 0);
  }
  int rr = kq << 2;
  #pragma unroll
  for(int i=0;i<4;i++){
    pdt[wid][rr+i][fr]      = a0[i];
    pdt[wid][rr+i][16+fr]   = a1[i];
  }
  __syncthreads();
  for(int e = tid; e < 512; e += 256){
    int r = e >> 5, s = e & 31;
    float v = pdt[0][r][s] + pdt[1][r][s] + pdt[2][r][s] + pdt[3][r][s];
    dtb[((long)b*SEQ + t0 + r)*32 + s] = v;
  }
}

// ---------------- scanAY with MFMA-precomputed da/ba ----------------
__global__ __launch_bounds__(256) void scanAY_mfma_kernel(const unsigned short* __restrict__ xz,
      const float* __restrict__ dtb, const float* __restrict__ cw,
      const unsigned short* __restrict__ wcomb,
      const float* __restrict__ dtbias_g, const float* __restrict__ dp_g,
      float2* __restrict__ chunk, unsigned short* __restrict__ y0s,
      unsigned short* __restrict__ as_s){
  __shared__ unsigned short abuf[64][32];          // 4 KiB
  __shared__ unsigned short dab[64*256*2];         // 64 KiB
  int c = blockIdx.x, db = blockIdx.y, b = blockIdx.z;
  int tid = threadIdx.x;
  int t0 = c*TC;
  {
    const float4* src = reinterpret_cast<const float4*>(dtb + ((long)b*SEQ + t0)*32);
    float4 v0 = src[tid*2], v1 = src[tid*2+1];
    bf16x8 o;
    o[0]=(short)f2bf(v0.x); o[1]=(short)f2bf(v0.y); o[2]=(short)f2bf(v0.z); o[3]=(short)f2bf(v0.w);
    o[4]=(short)f2bf(v1.x); o[5]=(short)f2bf(v1.y); o[6]=(short)f2bf(v1.z); o[7]=(short)f2bf(v1.w);
    *reinterpret_cast<bf16x8*>(&abuf[tid>>2][(tid&3)*8]) = o;
  }
  __syncthreads();
  {
    int w = tid >> 6, lane = tid & 63;
    int fr = lane & 15, kq = lane >> 4;
    bf16x8 zero = {0,0,0,0,0,0,0,0};
    bf16x8 bq[4], bp[4];
    #pragma unroll
    for(int nt=0; nt<4; nt++){
      int dcol = db*256 + w*64 + nt*16 + fr;
      bf16x8 wv = *reinterpret_cast<const bf16x8*>(wcomb + (long)dcol*32 + kq*8);
      bq[nt] = (kq<2) ? wv : zero;
      bp[nt] = (kq<2) ? zero : wv;
    }
    #pragma unroll
    for(int mt=0; mt<4; mt++){
      bf16x8 av = *reinterpret_cast<const bf16x8*>(&abuf[mt*16 + fr][kq*8]);
      #pragma unroll
      for(int nt=0; nt<4; nt++){
        f32x4 aq = __builtin_amdgcn_mfma_f32_16x16x32_bf16(av, bq[nt], (f32x4){0.f,0.f,0.f,0.f}, 0,0,0);
        f32x4 ap = __builtin_amdgcn_mfma_f32_16x16x32_bf16(av, bp[nt], (f32x4){0.f,0.f,0.f,0.f}, 0,0,0);
        int dl = w*64 + nt*16 + fr;
        #pragma unroll
        for(int i=0;i<4;i++){
          int t = mt*16 + kq*4 + i;
          unsigned int pack = (unsigned int)f2bf(aq[i]) | (((unsigned int)f2bf(ap[i]))<<16);
          *reinterpret_cast<unsigned int*>(&dab[(t*256 + dl)*2]) = pack;
        }
      }
    }
  }
  int d = db*256 + tid;
  float c0=cw[d*4],c1=cw[d*4+1],c2=cw[d*4+2],c3=cw[d*4+3];
  float bias = dtbias_g[d];
  float dp = dp_g[d];
  asm volatile("" : "+v"(c0),"+v"(c1),"+v"(c2),"+v"(c3),"+v"(bias),"+v"(dp));
  long base = ((long)b*SEQ + t0)*(2*DI) + d;
  float wm3 = (t0>0) ? bf2f(xz[base - 3*(2*DI)]) : 0.f;
  float wm2 = (t0>0) ? bf2f(xz[base - 2*(2*DI)]) : 0.f;
  float wm1 = (t0>0) ? bf2f(xz[base - 1*(2*DI)]) : 0.f;
  const unsigned short* xp = xz + base;
  long sidx = ((long)b*SEQ + t0)*DI + d;
  unsigned short* yp = y0s + sidx;
  unsigned short* ap2 = as_s + sidx;
  __syncthreads();
  float h = 0.f, P = 1.f;
  const unsigned int* dab32 = reinterpret_cast<const unsigned int*>(dab);
  for(int g=0; g<TC/8; g++){
    unsigned short xv[8];
    #pragma unroll
    for(int j=0;j<8;j++){ xv[j] = xp[(long)j*2*DI]; }
    xp += 8L*2*DI;
    #pragma unroll
    for(int j=0;j<8;j++){
      float wt = bf2f(xv[j]);
      float u = siluf(fmaf(c3,wt, fmaf(c2,wm1, fmaf(c1,wm2, c0*wm3))));
      wm3=wm2; wm2=wm1; wm1=wt;
      unsigned int pk = dab32[(g*8+j)*256 + tid];
      float da = bias + bf2f((unsigned short)(pk & 0xffffu));
      float ba = bf2f((unsigned short)(pk >> 16));
      float delta = fminf(fmaxf(fast_softplus(da), 1e-4f), 1.0f);
      float a = 1.0f - delta;
      h = fmaf(h, a, u*ba);
      P *= a;
      yp[(long)j*DI]  = f2bf(fmaf(dp, u, h));
      ap2[(long)j*DI] = f2bf(P);
    }
    yp += 8L*DI; ap2 += 8L*DI;
  }
  chunk[((long)b*DI + d)*NCHUNK + c] = make_float2(P, h);
}

// ---------------- scanAY (fallback) ----------------
__global__ __launch_bounds__(256) void scanAY_kernel(const unsigned short* __restrict__ xz,
      const float* __restrict__ dtb, const float* __restrict__ cw,
      const float* __restrict__ dtw_g, const float* __restrict__ dtbias_g,
      const float* __restrict__ bpw_g, const float* __restrict__ dp_g,
      float2* __restrict__ chunk, unsigned short* __restrict__ y,
      unsigned short* __restrict__ asz_s){
  __shared__ float dsb[TC*32];
  int c = blockIdx.x, db = blockIdx.y, b = blockIdx.z;
  int d = db*256 + threadIdx.x;
  int t0 = c*TC;
  {
    const float4* src = reinterpret_cast<const float4*>(dtb + ((long)b*SEQ + t0)*32);
    float4* dst = reinterpret_cast<float4*>(dsb);
    dst[threadIdx.x]       = src[threadIdx.x];
    dst[threadIdx.x + 256] = src[threadIdx.x + 256];
  }
  float c0=cw[d*4],c1=cw[d*4+1],c2=cw[d*4+2],c3=cw[d*4+3];
  f32x4 wq0 = *reinterpret_cast<const f32x4*>(dtw_g + d*16 + 0);
  f32x4 wq1 = *reinterpret_cast<const f32x4*>(dtw_g + d*16 + 4);
  f32x4 wq2 = *reinterpret_cast<const f32x4*>(dtw_g + d*16 + 8);
  f32x4 wq3 = *reinterpret_cast<const f32x4*>(dtw_g + d*16 + 12);
  f32x4 wp0 = *reinterpret_cast<const f32x4*>(bpw_g + d*16 + 0);
  f32x4 wp1 = *reinterpret_cast<const f32x4*>(bpw_g + d*16 + 4);
  f32x4 wp2 = *reinterpret_cast<const f32x4*>(bpw_g + d*16 + 8);
  f32x4 wp3 = *reinterpret_cast<const f32x4*>(bpw_g + d*16 + 12);
  float bias = dtbias_g[d];
  float dp = dp_g[d];
  asm volatile("" : "+v"(wq0),"+v"(wq1),"+v"(wq2),"+v"(wq3),
                    "+v"(wp0),"+v"(wp1),"+v"(wp2),"+v"(wp3),
                    "+v"(c0),"+v"(c1),"+v"(c2),"+v"(c3),"+v"(bias),"+v"(dp));
  long base = ((long)b*SEQ + t0)*(2*DI) + d;
  float wm3 = (t0>0) ? bf2f(xz[base - 3*(2*DI)]) : 0.f;
  float wm2 = (t0>0) ? bf2f(xz[base - 2*(2*DI)]) : 0.f;
  float wm1 = (t0>0) ? bf2f(xz[base - 1*(2*DI)]) : 0.f;
  const unsigned short* xp = xz + base;
  const unsigned short* zp = xz + base + DI;
  long sidx = ((long)b*SEQ + t0)*DI + d;
  unsigned short* yp = y + sidx;
  unsigned short* ap = asz_s + sidx;
  __syncthreads();
  float h = 0.f, P = 1.f;
  for(int g=0; g<TC/8; g++){
    unsigned short xv[8], zv[8];
    #pragma unroll
    for(int j=0;j<8;j++){ xv[j] = xp[(long)j*2*DI]; zv[j] = zp[(long)j*2*DI]; }
    xp += 8L*2*DI; zp += 8L*2*DI;
    const float* rp = dsb + g*8*32;
    #pragma unroll
    for(int j=0;j<8;j++){
      float wt = bf2f(xv[j]);
      float u = siluf(fmaf(c3,wt, fmaf(c2,wm1, fmaf(c1,wm2, c0*wm3))));
      wm3=wm2; wm2=wm1; wm1=wt;
      const f32x4* row = reinterpret_cast<const f32x4*>(rp + j*32);
      float da = bias + dot4(row[0],wq0) + dot4(row[1],wq1) + dot4(row[2],wq2) + dot4(row[3],wq3);
      float ba =        dot4(row[4],wp0) + dot4(row[5],wp1) + dot4(row[6],wp2) + dot4(row[7],wp3);
      float delta = fminf(fmaxf(fast_softplus(da), 1e-4f), 1.0f);
      float a = 1.0f - delta;
      h = fmaf(h, a, u*ba);
      P *= a;
      float sz = siluf(bf2f(zv[j]));
      yp[(long)j*DI] = f2bf(fmaf(dp, u, h) * sz);
      ap[(long)j*DI] = f2bf(P * sz);
    }
    yp += 8L*DI; ap += 8L*DI;
  }
  chunk[((long)b*DI + d)*NCHUNK + c] = make_float2(P, h);
}

// ---------------- h0 table: prefix-combine chunk summaries ----------------
__global__ __launch_bounds__(256) void h0_kernel(const float2* __restrict__ chunk,
                                                 float* __restrict__ h0tab){
  int idx = blockIdx.x*256 + threadIdx.x;
  int b = idx / DI, d = idx - b*DI;
  const float2* cb = chunk + ((long)b*DI + d)*NCHUNK;
  float h0 = 0.f;
  for(int c=0; c<NCHUNK; c++){
    h0tab[((long)b*NCHUNK + c)*DI + d] = h0;
    float2 ps = cb[c];
    h0 = fmaf(ps.x, h0, ps.y);
  }
}

// ---------------- fixup_z: y = (y0 + h0*A) * silu(z) ----------------
__global__ __launch_bounds__(256) void fixup_z_kernel(const unsigned short* __restrict__ as_s,
      const float* __restrict__ h0tab, const unsigned short* __restrict__ xz,
      unsigned short* __restrict__ y){
  int i = (blockIdx.x*256 + threadIdx.x)*8;
  int bt = i / DI;
  int d  = i - bt*DI;
  int b  = bt >> 11;
  int c  = (bt & 2047) >> 6;
  const float* hp = h0tab + ((long)b*NCHUNK + c)*DI + d;
  f32x4 h0a = *reinterpret_cast<const f32x4*>(hp);
  f32x4 h0b = *reinterpret_cast<const f32x4*>(hp + 4);
  bf16x8 yv = *reinterpret_cast<const bf16x8*>(y + i);
  bf16x8 av = *reinterpret_cast<const bf16x8*>(as_s + i);
  bf16x8 zv = *reinterpret_cast<const bf16x8*>(xz + (long)bt*(2*DI) + DI + d);
  bf16x8 o;
  #pragma unroll
  for(int j=0;j<8;j++){
    float h0 = (j<4) ? h0a[j] : h0b[j-4];
    float v = fmaf(h0, bf2f((unsigned short)av[j]), bf2f((unsigned short)yv[j]));
    o[j] = (short)f2bf(v * siluf(bf2f((unsigned short)zv[j])));
  }
  *reinterpret_cast<bf16x8*>(y + i) = o;
}

// ---------------- fixup (fallback): y += h0 * asz ----------------
__global__ __launch_bounds__(256) void fixup_kernel(const unsigned short* __restrict__ asz_s,
      const float* __restrict__ h0tab, unsigned short* __restrict__ y){
  int i = (blockIdx.x*256 + threadIdx.x)*8;
  int bt = i / DI;
  int d  = i - bt*DI;
  int b  = bt >> 11;
  int c  = (bt & 2047) >> 6;
  const float* hp = h0tab + ((long)b*NCHUNK + c)*DI + d;
  f32x4 h0a = *reinterpret_cast<const f32x4*>(hp);
  f32x4 h0b = *reinterpret_cast<const f32x4*>(hp + 4);
  bf16x8 yv = *reinterpret_cast<const bf16x8*>(y + i);
  bf16x8 av = *reinterpret_cast<const bf16x8*>(asz_s + i);
  bf16x8 o;
  #pragma unroll
  for(int j=0;j<8;j++){
    float h0 = (j<4) ? h0a[j] : h0b[j-4];
    o[j] = (short)f2bf(fmaf(h0, bf2f((unsigned short)av[j]), bf2f((unsigned short)yv[j])));
  }
  *reinterpret_cast<bf16x8*>(y + i) = o;
}

// ---------------- launch ----------------
extern "C" void kernel_launch(void* const* d_in, const int* in_sizes, int n_in,
                              void* d_out, int out_size, void* d_ws, size_t ws_size,
                              hipStream_t stream){
  const int*   tokens  = (const int*)  d_in[0];
  const int*   emotion = (const int*)  d_in[1];
  const int*   style   = (const int*)  d_in[2];
  const int*   keysig  = (const int*)  d_in[3];
  const int*   modei   = (const int*)  d_in[4];
  const float* bpm     = (const float*)d_in[5];
  const float* tok_emb = (const float*)d_in[6];
  const float* emo_emb = (const float*)d_in[7];
  const float* sty_emb = (const float*)d_in[8];
  const float* key_emb = (const float*)d_in[9];
  const float* mode_emb= (const float*)d_in[10];
  const float* bpm_w   = (const float*)d_in[11];
  const float* bpm_b   = (const float*)d_in[12];
  const float* cond_w  = (const float*)d_in[13];
  const float* cond_b  = (const float*)d_in[14];
  const float* pos_emb = (const float*)d_in[15];
  const float* ln_g    = (const float*)d_in[16];
  const float* ln_b    = (const float*)d_in[17];
  const float* in_w    = (const float*)d_in[18];
  const float* conv_w  = (const float*)d_in[19];
  const float* xproj_w = (const float*)d_in[20];
  const float* dt_w    = (const float*)d_in[21];
  const float* dt_b    = (const float*)d_in[22];
  const float* bproj_w = (const float*)d_in[23];
  const float* d_param = (const float*)d_in[24];
  const float* out_w   = (const float*)d_in[25];
  const float* final_g = (const float*)d_in[26];
  const float* final_b = (const float*)d_in[27];
  const float* head_w  = (const float*)d_in[28];
  const float* head_b  = (const float*)d_in[29];

  // workspace layout: base 215,244,800 B; +h0tab +asz -> 267,149,312; +wcomb -> 267,935,744;
  // +inwb_all (all-layer in_w bf16) -> 305,684,480
  char* ws = (char*)d_ws;
  float*          x       = (float*)(ws + 0L);                    //  50,331,648
  unsigned short* hy      = (unsigned short*)(ws + 50331648L);    //  50,331,648
  unsigned short* xz      = (unsigned short*)(ws + 100663296L);   // 100,663,296
  float*          dtbuf   = (float*)(ws + 201326592L);            //   2,097,152
  float2*         chunk   = (float2*)(ws + 203423744L);           //   3,145,728
  float*          condv   = (float*)(ws + 206569472L);            //      24,576
  unsigned short* inwb    = (unsigned short*)(ws + 206594048L);   //   4,718,592
  unsigned short* outwb   = (unsigned short*)(ws + 211312640L);   //   2,359,296
  unsigned short* headwb  = (unsigned short*)(ws + 213671936L);   //     786,432
  unsigned short* wbf_all = (unsigned short*)(ws + 214458368L);   //     786,432 -> 215,244,800
  float*          h0tab   = (float*)(ws + 215244800L);            //   1,572,864
  unsigned short* asz_s   = (unsigned short*)(ws + 216817664L);   //  50,331,648 -> 267,149,312
  unsigned short* wcombb  = (unsigned short*)(ws + 267149312L);   //     786,432 -> 267,935,744
  unsigned short* inwb_all= (unsigned short*)(ws + 267935744L);   //  37,748,736 -> 305,684,480

  const bool use_mfma = (ws_size >= 267935744UL);
  const bool use_pre  = (ws_size >= 305684480UL);

  unsigned short* h_bf = hy;        // [BT, DM]
  unsigned short* y_bf = hy;        // [BT, DI]
  unsigned short* xfin = hy;        // [BT, DM]

  cvt_bf16_kernel<<<128,256,0,stream>>>((const float4*)head_w,(ushort4*)headwb, NVOCAB*DM/4);
  cvt_bf16_kernel<<<384,256,0,stream>>>((const float4*)xproj_w,(ushort4*)wbf_all, NL*32*DI/4);
  if(use_mfma)
    wcomb_kernel<<<NL*DI*32/256,256,0,stream>>>(dt_w, bproj_w, wcombb);
  if(use_pre)
    cvt_bf16_kernel<<<2048,256,0,stream>>>((const float4*)in_w, (ushort4*)inwb_all, NL*2*DI*DM/4);
  cond_kernel<<<dim3(DM/4,8),256,0,stream>>>(emotion, style, keysig, modei, bpm, emo_emb, sty_emb,
        key_emb, mode_emb, bpm_w, bpm_b, cond_w, cond_b, condv);
  embed_kernel<<<BT,192,0,stream>>>(tokens, tok_emb, condv, pos_emb, x);

  for(int l=0; l<NL; l++){
    const unsigned short* inw_l;
    if(use_pre){
      cvt_bf16_kernel<<<512,256,0,stream>>>((const float4*)(out_w + (long)l*DM*DI), (ushort4*)outwb, DM*DI/4);
      inw_l = inwb_all + (long)l*2*DI*DM;
    } else {
      cvt2_bf16_kernel<<<1536,256,0,stream>>>((const float4*)(in_w  + (long)l*2*DI*DM), (ushort4*)inwb,  2*DI*DM/4,
                                              (const float4*)(out_w + (long)l*DM*DI),   (ushort4*)outwb, DM*DI/4);
      inw_l = inwb;
    }
    ln_bf16_kernel<<<BT/4,256,0,stream>>>(x, ln_g + l*DM, ln_b + l*DM, h_bf);
    gemm256<3><<<dim3(2*DI/256, BT/256),512,0,stream>>>(h_bf, inw_l, xz, DM, 2*DI);
    xproj_kernel<<<BT/16,256,0,stream>>>(xz, conv_w + l*DI*4, wbf_all + (long)l*32*DI, dtbuf);
    if(use_mfma){
      scanAY_mfma_kernel<<<dim3(NCHUNK,6,BATCH),256,0,stream>>>(xz, dtbuf, conv_w + l*DI*4,
            wcombb + (long)l*DI*32, dt_b + l*DI, d_param + l*DI, chunk, y_bf, asz_s);
      h0_kernel<<<48,256,0,stream>>>(chunk, h0tab);
      fixup_z_kernel<<<BT*DI/(256*8),256,0,stream>>>(asz_s, h0tab, xz, y_bf);
    } else {
      scanAY_kernel<<<dim3(NCHUNK,6,BATCH),256,0,stream>>>(xz, dtbuf, conv_w + l*DI*4,
            dt_w + l*DI*DS, dt_b + l*DI, bproj_w + l*DI*DS, d_param + l*DI, chunk, y_bf, asz_s);
      h0_kernel<<<48,256,0,stream>>>(chunk, h0tab);
      fixup_kernel<<<BT*DI/(256*8),256,0,stream>>>(asz_s, h0tab, y_bf);
    }
    gemm_lds<1><<<dim3(DM/128, BT/128),256,0,stream>>>(y_bf, outwb, x, nullptr, DI, DM);
  }
  ln_bf16_kernel<<<BT/4,256,0,stream>>>(x, final_g, final_b, xfin);
  gemm_lds<2><<<dim3(NVOCAB/128, BT/128),256,0,stream>>>(xfin, headwb, d_out, head_b, DM, NVOCAB);
}